// Round 8
// baseline (303.690 us; speedup 1.0000x reference)
//
#include <hip/hip_runtime.h>
#include <stdint.h>

#define NB 16
#define NC 256
#define NH 48
#define NW 160
#define HW (NH*NW)        // 7680
#define NP (NB*HW)        // 122880

static __device__ __forceinline__ unsigned short f2bf(float f){
  union { float f; uint32_t u; } v; v.f = f;
  uint32_t u = v.u;
  uint32_t r = (u + 0x7FFFu + ((u >> 16) & 1u)) >> 16;
  return (unsigned short)r;
}
static __device__ __forceinline__ float bf2f(unsigned short h){
  union { float f; uint32_t u; } v; v.u = ((uint32_t)h) << 16; return v.f;
}

// ---- KW: produce FRAGMENT-MAJOR weights so kb's A-loads are lane-contiguous.
__global__ __launch_bounds__(256) void kw_conv(const float* __restrict__ w_ext,
                                               const float* __restrict__ w_disp,
                                               unsigned short* __restrict__ WbF,
                                               unsigned short* __restrict__ WtapF){
  int d = blockIdx.x * 256 + threadIdx.x;
  if (blockIdx.x < 256){
    int j  = d & 7;
    int lane = (d >> 3) & 63;
    int mi = (d >> 9) & 3;
    int w  = (d >> 11) & 3;
    int ks = d >> 13;
    int m = w * 64 + mi * 16 + (lane & 15);
    int k = ks * 32 + (lane >> 4) * 8 + j;
    WbF[d] = f2bf(w_ext[m * 257 + 1 + k]);
  } else {
    int d2 = d - 65536;                 // 0..4095
    int j  = d2 & 7;
    int lane = (d2 >> 3) & 63;
    int ks = d2 >> 9;
    int tap = lane & 15;
    int k = ks * 32 + (lane >> 4) * 8 + j;
    WtapF[d2] = (tap < 9) ? f2bf(w_disp[k * 9 + tap]) : (unsigned short)0;
  }
}

// ---- KB: fused transpose-stage + GEMM, 32-px tile, 4 blocks/CU (TLP test).
//   Tile halved vs R7: acc 4x2 (32 AGPR), staging 16 float2 (32 VGPR),
//   LDS 16 KB -> launch_bounds(256,4) = 16 waves/CU (~50% occupancy).
//   Plain compiler-scheduled staging; one barrier; 8 compute steps.
typedef __attribute__((ext_vector_type(8))) short bf16x8;
typedef __attribute__((ext_vector_type(4))) short bf16x4;
typedef __attribute__((ext_vector_type(4))) float f32x4;

__global__ __launch_bounds__(256, 4) void kb_gemm(
    const float* __restrict__ x,             // [NB][NC][HW] fp32
    const unsigned short* __restrict__ Wb,   // fragment-major, 65536 shorts
    const unsigned short* __restrict__ Wtap, // fragment-major, 4096 shorts
    unsigned short* __restrict__ U,          // [NB][64][HW][4] bf16
    float* __restrict__ T)                   // [9][NP] fp32
{
  // [ks][unit(2)][(n15 + kq*16)*8 + j] : 8 * 2 * 512 shorts = 16 KB
  __shared__ __align__(16) unsigned short smem[8 * 1024];
  int bx = blockIdx.x;            // 3840 = 16 b * 240 nt
  int b  = bx / 240;
  int nt = bx - b * 240;
  int p0 = nt * 32;               // hw offset within image (32 | 7680)

  int tid  = threadIdx.x;
  int lane = tid & 63;
  int w    = tid >> 6;            // wave 0..3 ; o-quarter
  int l15 = lane & 15;
  int lq  = lane >> 4;

  // staging role: thread = (pixel pair q, 16-ch group cg)
  int q  = tid & 15;              // px pair: n = 2q, 2q+1
  int cg = tid >> 4;              // 0..15 : channels cg*16 .. cg*16+15
  const float* xs = x + ((size_t)b * NC + (size_t)cg * 16) * HW + p0 + 2 * q;

  float2 v[16];
  #pragma unroll
  for (int i = 0; i < 16; ++i)
    v[i] = *(const float2*)(xs + (size_t)i * HW);

  f32x4 zero = {0.f, 0.f, 0.f, 0.f};
  f32x4 acc[4][2];
  f32x4 acct[2];
  #pragma unroll
  for (int mi = 0; mi < 4; ++mi){
    #pragma unroll
    for (int ni = 0; ni < 2; ++ni) acc[mi][ni] = zero;
  }
  acct[0] = zero; acct[1] = zero;

  // ---- convert + LDS write --------------------------------------------
  // channel c = cg*16 + i :  ks = cg>>1, kq = (cg*2 + (i>>3)) & 3, j = i&7
  {
    int ks = cg >> 1;
    int un = q >> 3;                        // (2q)>>4
    int n15a = (2 * q) & 15;
    unsigned short* swb = smem + ks * 1024 + un * 512;
    #pragma unroll
    for (int g = 0; g < 2; ++g){
      int kq = (cg * 2 + g) & 3;
      unsigned short ha[8], hb[8];
      #pragma unroll
      for (int j = 0; j < 8; ++j){
        ha[j] = f2bf(v[8 * g + j].x);
        hb[j] = f2bf(v[8 * g + j].y);
      }
      *(bf16x8*)(swb + (n15a     + kq * 16) * 8) = *(bf16x8*)ha;
      *(bf16x8*)(swb + (n15a + 1 + kq * 16) * 8) = *(bf16x8*)hb;
    }
  }
  __syncthreads();

  // ---- compute phase: 8 steps, plain A loads (TLP hides L2 latency) ----
  #pragma unroll
  for (int t = 0; t < 8; ++t){
    bf16x8 af[4];
    #pragma unroll
    for (int mi = 0; mi < 4; ++mi)
      af[mi] = *(const bf16x8*)(Wb + ((t * 16 + w * 4 + mi) << 9) + lane * 8);
    bf16x8 bg[2];
    #pragma unroll
    for (int ni = 0; ni < 2; ++ni)
      bg[ni] = *(const bf16x8*)(smem + t * 1024 + ni * 512 + lane * 8);
    #pragma unroll
    for (int mi = 0; mi < 4; ++mi)
      #pragma unroll
      for (int ni = 0; ni < 2; ++ni)
        acc[mi][ni] = __builtin_amdgcn_mfma_f32_16x16x32_bf16(af[mi], bg[ni],
                                                      acc[mi][ni], 0, 0, 0);
    if (w == 0){
      bf16x8 at = *(const bf16x8*)(Wtap + (t << 9) + lane * 8);
      #pragma unroll
      for (int ni = 0; ni < 2; ++ni)
        acct[ni] = __builtin_amdgcn_mfma_f32_16x16x32_bf16(at, bg[ni],
                                                       acct[ni], 0, 0, 0);
    }
  }

  // epilogue U2[b][og][p][4]: lane packs 4 consecutive-o values into one
  // 8-B store; 16 lanes = consecutive px = 128 B contiguous.
  #pragma unroll
  for (int mi = 0; mi < 4; ++mi){
    int og = w * 16 + mi * 4 + lq;          // o >> 2
    #pragma unroll
    for (int ni = 0; ni < 2; ++ni){
      int n = ni * 16 + l15;
      unsigned short h[4];
      #pragma unroll
      for (int r = 0; r < 4; ++r) h[r] = f2bf(acc[mi][ni][r]);
      *(bf16x4*)(U + (((size_t)b * 64 + og) * HW + p0 + n) * 4) = *(bf16x4*)h;
    }
  }
  // epilogue T (wave 0): row = lq*4+r = tap index, keep rows 0..8
  if (w == 0){
    #pragma unroll
    for (int ni = 0; ni < 2; ++ni){
      int n = ni * 16 + l15;
      #pragma unroll
      for (int r = 0; r < 4; ++r){
        int k = lq * 4 + r;
        if (k < 9)
          T[(size_t)k * NP + (size_t)b * HW + p0 + n] = acct[ni][r];
      }
    }
  }
}

// ---- KP: per-pixel grid params (wy, dlerp, off0, off1) ----------------------
__global__ __launch_bounds__(256) void kp_grid(
    const float* __restrict__ P2, const float* __restrict__ b_disp,
    const float* __restrict__ T, float4* __restrict__ pre)
{
  int p = blockIdx.x * 256 + threadIdx.x;   // 0..122879
  int b  = p / HW;
  int hw = p - b * HW;
  int y  = hw / NW;
  int xx = hw - y * NW;

  float d = 0.f;
  #pragma unroll
  for (int ky = 0; ky < 3; ++ky){
    int yy2 = y + ky - 1;
    if (yy2 < 0 || yy2 >= NH) continue;
    #pragma unroll
    for (int kx = 0; kx < 3; ++kx){
      int xx2 = xx + kx - 1;
      if (xx2 < 0 || xx2 >= NW) continue;
      d += T[(size_t)(ky * 3 + kx) * NP + b * HW + yy2 * NW + xx2];
    }
  }
  float th = tanhf(d + b_disp[0]);

  float fy = P2[b * 12 + 5] * 0.0625f;
  float cy = P2[b * 12 + 6] * 0.0625f;
  float Ty = P2[b * 12 + 7] * 0.0625f;

  float ysb   = fmaxf(1.535f * ((float)y - cy) / 1.765f, 0.f) * (1.f / 24.f);
  float ybase = -1.f + (float)y * (2.f / 47.f);
  float gy = ybase + ysb + 0.1f * th;
  float iy = fminf(fmaxf((gy + 1.f) * 0.5f * 47.f, 0.f), 47.f);
  float fiy0 = floorf(iy);
  float wy = iy - fiy0;
  int iy0 = (int)fiy0;
  int iy1 = min(iy0 + 1, 47);

  float inv_den = 1.f / (fabsf(fy * 1.65f + Ty) + 1e-10f);
  float dr0 = fmaxf(fy * 0.54f * ((float)iy0 - cy) * inv_den, 0.f);
  float dr1 = fmaxf(fy * 0.54f * ((float)iy1 - cy) * inv_den, 0.f);
  float dlerp = (1.f - wy) * dr0 + wy * dr1;

  float4 pr;
  pr.x = wy; pr.y = dlerp;
  pr.z = __int_as_float(iy0 * NW + xx);
  pr.w = __int_as_float(iy1 * NW + xx);
  pre[p] = pr;
}

// ---- KC: lerp + matvec-residual ReLU; U2 rows read as 8-B coalesced --------
__global__ __launch_bounds__(256) void kc_epilogue(
    const float* __restrict__ x, const float* __restrict__ w_ext,
    const float* __restrict__ b_ext, const float* __restrict__ alpha,
    const unsigned short* __restrict__ U, const float4* __restrict__ pre,
    float* __restrict__ out)
{
  int bx = blockIdx.x;            // 3840 = 480 ptile * 8 cg
  int ptile = bx >> 3;
  int cg    = bx & 7;
  int p = ptile * 256 + threadIdx.x;
  int b  = p / HW;
  int hw = p - b * HW;

  float4 pr = pre[p];
  float wy    = pr.x;
  float dlerp = pr.y;
  int off0 = __float_as_int(pr.z);
  int off1 = __float_as_int(pr.w);
  float w1 = 1.f - wy;
  float al = alpha[0];

  int og0 = cg * 8;               // o block: o = og*4 + r
  const unsigned short* Ua = U + (((size_t)b * 64 + og0) * HW) * 4;
  bf16x4 ua[8], ub[8];
  #pragma unroll
  for (int i = 0; i < 8; ++i){
    ua[i] = *(const bf16x4*)(Ua + ((size_t)i * HW + off0) * 4);
    ub[i] = *(const bf16x4*)(Ua + ((size_t)i * HW + off1) * 4);
  }

  size_t base0 = (size_t)(b * NC) * HW;
  const float* xb = x + base0 + hw;
  float* ob = out + base0 + hw;

  int o0 = cg * 32;
  #pragma unroll
  for (int i = 0; i < 8; ++i){
    #pragma unroll
    for (int r = 0; r < 4; ++r){
      int o = o0 + i * 4 + r;
      float u0 = bf2f((unsigned short)ua[i][r]);
      float u1 = bf2f((unsigned short)ub[i][r]);
      float val = w1 * u0 + wy * u1 + w_ext[o * 257] * dlerp + b_ext[o];
      float rr = xb[(size_t)o * HW] + al * val;
      ob[(size_t)o * HW] = fmaxf(rr, 0.f);
    }
  }
}

// ---------------------------------------------------------------------------
extern "C" void kernel_launch(void* const* d_in, const int* in_sizes, int n_in,
                              void* d_out, int out_size, void* d_ws, size_t ws_size,
                              hipStream_t stream) {
  const float* features = (const float*)d_in[0];
  const float* P2       = (const float*)d_in[1];
  const float* w_disp   = (const float*)d_in[2];
  const float* b_disp   = (const float*)d_in[3];
  const float* w_ext    = (const float*)d_in[4];
  const float* b_ext    = (const float*)d_in[5];
  const float* alpha    = (const float*)d_in[6];
  float* out = (float*)d_out;

  char* ws = (char*)d_ws;
  const size_t U_bytes   = (size_t)NP * 256 * 2;    // 62,914,560
  const size_t T_bytes   = (size_t)9 * NP * 4;      //  4,423,680
  const size_t pre_bytes = (size_t)NP * 16;         //  1,966,080
  unsigned short* U    = (unsigned short*)ws;
  float*          T    = (float*)(ws + U_bytes);
  float4*         pre  = (float4*)(ws + U_bytes + T_bytes);
  unsigned short* Wb   = (unsigned short*)(ws + U_bytes + T_bytes + pre_bytes);
  unsigned short* Wtap = Wb + 256 * 256;

  hipLaunchKernelGGL(kw_conv,     dim3(272),  dim3(256), 0, stream, w_ext, w_disp, Wb, Wtap);
  hipLaunchKernelGGL(kb_gemm,     dim3(3840), dim3(256), 0, stream, features, Wb, Wtap, U, T);
  hipLaunchKernelGGL(kp_grid,     dim3(480),  dim3(256), 0, stream, P2, b_disp, T, pre);
  hipLaunchKernelGGL(kc_epilogue, dim3(3840), dim3(256), 0, stream,
                     features, w_ext, b_ext, alpha, U, pre, out);
}